// Round 2
// baseline (174.745 us; speedup 1.0000x reference)
//
#include <hip/hip_runtime.h>

// Problem: x [64,128,56,56] fp32; act_codes [C*H*W] int32 in [0,6).
// out[b, n] = act[act_codes[n]](x[b, n]) with n over C*H*W = 401408.
// N/4 = 100352 = 392 * 256 exactly -> exact 2D grid, no bounds checks.
//
// R1: rcp/exp2 peephole gave ~0 net; kernel is VALU-issue-bound across the
// whole body, not just the divides.
// R2: structural cut — all nonlinear acts are ONE sigmoid evaluation:
//   sigmoid(x) = s(x)
//   tanh(x)    = 2*s(2x) - 1
//   gelu(x)    = x * s(2u),  2u = x*(1.5957691216 + 0.0713548162*x^2)
//   elu(x<0)   = exp(x) - 1 = e - 1   (e = exp(-|t|) with t = x)
// One code-selected argument t, one v_exp_f32, one v_rcp_f32 per element;
// ~26 VALU / 2 trans per element vs ~40 / 5 before.

#define N4 100352   // (128*56*56)/4
#define GX 392      // N4 / 256
#define GY 64       // batch

typedef float f32x4 __attribute__((ext_vector_type(4)));

__device__ __forceinline__ float apply_act(float x, int c) {
    const float L2E = 1.4426950408889634f;   // log2(e)

    bool c1 = (c == 1), c2 = (c == 2), c3 = (c == 3), c4 = (c == 4), c5 = (c == 5);
    bool pos = (x >= 0.f);

    // code-selected sigmoid argument: t = x (c0/c1/c3/c4), 2x (c2), 2u (c5)
    float x2 = x * x;
    float tg = fmaf(0.0713548162f, x2, 1.5957691216f);  // 2u / x
    float tm = c2 ? 2.f : (c5 ? tg : 1.f);
    float t  = x * tm;                                   // sign(t) == sign(x)

    // stable sigmoid core: s = sigmoid(t); e = exp(-|t|)
    float e = __builtin_amdgcn_exp2f(-L2E * fabsf(t));   // (0,1], never overflows
    float r = __builtin_amdgcn_rcpf(1.f + e);            // v_rcp_f32, ~1 ulp
    float s = pos ? r : e * r;

    // sigmoid family: result = a*s + b   (c1: s, c2: 2s-1, c5: x*s)
    float a = c5 ? x : (c2 ? 2.f : 1.f);
    float b = c2 ? -1.f : 0.f;
    float fam = fmaf(a, s, b);

    // trivial family (c0/c3/c4): pos-side is x for all; neg-side selected.
    // c3 neg: e - 1 (here t = x, so e = exp(x));  c4 neg: 0.01x;  c0 neg: 0
    float neg  = c3 ? (e - 1.f) : (c4 ? 0.01f * x : 0.f);
    float triv = pos ? x : neg;

    bool isfam = c1 | c2 | c5;
    return isfam ? fam : triv;
}

__global__ __launch_bounds__(256) void act_select_kernel(
    const f32x4* __restrict__ x,
    const int4*  __restrict__ codes,
    f32x4*       __restrict__ out) {
    int n   = blockIdx.x * 256 + threadIdx.x;   // [0, N4)
    int idx = blockIdx.y * N4 + n;              // max 6,422,527 < 2^31

    f32x4 v = x[idx];
    int4  c = codes[n];                         // L2/L3-resident after first batch row

    f32x4 o;
    o.x = apply_act(v.x, c.x);
    o.y = apply_act(v.y, c.y);
    o.z = apply_act(v.z, c.z);
    o.w = apply_act(v.w, c.w);

    // out is write-once, never re-read this iteration: bypass caches so x
    // stays L3-resident across bench iterations
    __builtin_nontemporal_store(o, &out[idx]);
}

extern "C" void kernel_launch(void* const* d_in, const int* in_sizes, int n_in,
                              void* d_out, int out_size, void* d_ws, size_t ws_size,
                              hipStream_t stream) {
    const f32x4* x     = (const f32x4*)d_in[0];
    const int4*  codes = (const int4*)d_in[1];
    f32x4*       out   = (f32x4*)d_out;

    dim3 grid(GX, GY);
    act_select_kernel<<<grid, 256, 0, stream>>>(x, codes, out);
}